// Round 1
// baseline (74.652 us; speedup 1.0000x reference)
//
#include <hip/hip_runtime.h>
#include <math.h>

#define NN 768
#define DD 128
#define CAP 192   // max neighbors stored per row (binomial(768,0.04): mean~31, CAP=192 is >20 sigma)

__device__ __forceinline__ float wave_reduce(float v) {
    #pragma unroll
    for (int o = 32; o > 0; o >>= 1) v += __shfl_down(v, o, 64);
    return v;
}

// ---------------- Kernel 1: per-row scalars: x2[i], s_left[i], s_right[i] ----------------
// s_left[i] = g0_i * <x_i, w[:D]>, s_right[i] = g0_i * <x_i, w[D:]>, g0 = atanh(clip(r))/max(r,MIN)
__global__ void precompute_kernel(const float* __restrict__ x,
                                  const float* __restrict__ att_w,
                                  float* __restrict__ x2a,
                                  float* __restrict__ sL,
                                  float* __restrict__ sR) {
    __shared__ float red[3][2];
    int i = blockIdx.x, t = threadIdx.x;  // 128 threads
    float v  = x[i * DD + t];
    float wl = att_w[t];
    float wr = att_w[DD + t];
    float a = wave_reduce(v * v);
    float b = wave_reduce(v * wl);
    float c = wave_reduce(v * wr);
    int wid = t >> 6, lane = t & 63;
    if (lane == 0) { red[0][wid] = a; red[1][wid] = b; red[2][wid] = c; }
    __syncthreads();
    if (t == 0) {
        float x2 = red[0][0] + red[0][1];
        float dl = red[1][0] + red[1][1];
        float dr = red[2][0] + red[2][1];
        float r  = sqrtf(x2);
        float rc = fmaxf(r, 1e-15f);
        float g0 = atanhf(fminf(rc, 1.0f - 1e-7f)) / rc;
        x2a[i] = x2;
        sL[i]  = g0 * dl;
        sR[i]  = g0 * dr;
    }
}

// ---------------- Kernel 2: per-row neighbor compaction + pair scalar coefficients -------
// For each nonzero adj[i][j]:
//   dot = <x_i,x_j>;  alpha = 1 - 2 dot + y2;  beta = 1 - x2_i
//   denom = 1 - 2 dot + x2_i*y2  (clamped)
//   |sub|^2 = (alpha^2 x2_i - 2 alpha beta dot + beta^2 y2)/denom^2
//   g = atanh(clip(|sub|))/max(|sub|,MIN);  w = sigmoid(sL_i + sR_j + b0) * adj
//   common = w * max(beta,MIN) * g / denom
//   coefA (on x_i) = -common*alpha  (row-summed);  coefB (on x_j) = common*beta (stored)
__global__ void pair_kernel(const float* __restrict__ x,
                            const float* __restrict__ adj,
                            const float* __restrict__ x2a,
                            const float* __restrict__ sL,
                            const float* __restrict__ sR,
                            const float* __restrict__ att_b,
                            float* __restrict__ rowA,
                            int* __restrict__ cnt,
                            int* __restrict__ Jlist,
                            float* __restrict__ Blist) {
    __shared__ float xi[DD];
    __shared__ int   list[NN];
    __shared__ float aval[NN];
    __shared__ float dots[NN];
    __shared__ int   counter;
    __shared__ float red[4];

    int i = blockIdx.x, t = threadIdx.x;  // 256 threads
    if (t < DD) xi[t] = x[i * DD + t];
    if (t == 0) counter = 0;
    __syncthreads();

    // Phase 1: compact nonzero columns of this adjacency row
    for (int j = t; j < NN; j += 256) {
        float a = adj[i * NN + j];
        if (a != 0.0f) {
            int k = atomicAdd(&counter, 1);
            list[k] = j;
            aval[k] = a;
        }
    }
    __syncthreads();
    int n = counter;

    // Phase 2a: dot products, one wave per compact item
    int wid = t >> 6, lane = t & 63;
    for (int k = wid; k < n; k += 4) {
        int j = list[k];
        float v = xi[lane] * x[j * DD + lane] + xi[lane + 64] * x[j * DD + lane + 64];
        #pragma unroll
        for (int o = 32; o > 0; o >>= 1) v += __shfl_down(v, o, 64);
        if (lane == 0) dots[k] = v;
    }
    __syncthreads();

    // Phase 2b: scalar pair math on compact items
    float x2i    = x2a[i];
    float beta   = 1.0f - x2i;
    float factor = fmaxf(beta, 1e-15f);   // 2/(sqrt_c*lambda_i)
    float sLi    = sL[i];
    float b0     = att_b[0];
    float asum   = 0.0f;
    for (int k = t; k < n; k += 256) {
        int   j   = list[k];
        float dot = dots[k];
        float y2  = x2a[j];
        float z   = sLi + sR[j] + b0;
        float w   = aval[k] / (1.0f + __expf(-z) * 0.0f + expf(-z) * 1.0f - expf(-z) * 0.0f); // placeholder avoided below
        w = aval[k] / (1.0f + expf(-z));
        float alpha  = 1.0f - 2.0f * dot + y2;
        float denom  = 1.0f - 2.0f * dot + x2i * y2;
        float denomc = fmaxf(denom, 1e-15f);
        float sn2 = fmaxf((alpha * alpha * x2i - 2.0f * alpha * beta * dot + beta * beta * y2)
                          / (denomc * denomc), 0.0f);
        float sn = fmaxf(sqrtf(sn2), 1e-15f);
        float g  = atanhf(fminf(sn, 1.0f - 1e-7f)) / sn;
        float common = w * factor * g / denomc;
        asum += -common * alpha;
        if (k < CAP) {
            Blist[i * CAP + k] = common * beta;
            Jlist[i * CAP + k] = j;
        }
    }
    // block reduce asum (4 waves)
    asum = wave_reduce(asum);
    if ((t & 63) == 0) red[t >> 6] = asum;
    __syncthreads();
    if (t == 0) {
        rowA[i] = red[0] + red[1] + red[2] + red[3];
        cnt[i]  = (n < CAP) ? n : CAP;
    }
}

// ---------------- Kernel 3: sparse aggregation + expmap + mobius_add + proj --------------
__device__ __forceinline__ float block_reduce_128(float v, float* red) {
    int t = threadIdx.x, wid = t >> 6, lane = t & 63;
    v = wave_reduce(v);
    if (lane == 0) red[wid] = v;
    __syncthreads();
    float r = red[0] + red[1];
    __syncthreads();
    return r;
}

__global__ void agg_kernel(const float* __restrict__ x,
                           const float* __restrict__ x2a,
                           const float* __restrict__ rowA,
                           const int* __restrict__ cnt,
                           const int* __restrict__ Jlist,
                           const float* __restrict__ Blist,
                           float* __restrict__ out) {
    __shared__ float red[2];
    __shared__ int   jj[CAP];
    __shared__ float bb[CAP];
    int i = blockIdx.x, t = threadIdx.x;  // 128 threads, t = dim
    int n = cnt[i];
    for (int k = t; k < n; k += DD) {
        jj[k] = Jlist[i * CAP + k];
        bb[k] = Blist[i * CAP + k];
    }
    __syncthreads();

    float xv  = x[i * DD + t];
    float acc = 0.0f;
    for (int k = 0; k < n; ++k) {
        acc += bb[k] * x[jj[k] * DD + t];
    }
    float u = rowA[i] * xv + acc;   // support_t[i, t]

    // expmap(u, x_i) then mobius_add(x_i, second) then proj
    float un2 = block_reduce_128(u * u, red);
    float xu  = block_reduce_128(xv * u, red);

    float x2i    = x2a[i];
    float lamfac = fmaxf(1.0f - x2i, 1e-15f);        // 2/lambda_i
    float un     = fmaxf(sqrtf(un2), 1e-15f);
    float th     = tanhf(un / lamfac);
    float s      = th / un;                           // second = s * u
    float y2     = s * s * un2;
    float xy     = s * xu;
    float c1     = 1.0f + 2.0f * xy + y2;
    float c2     = 1.0f - x2i;
    float den    = fmaxf(1.0f + 2.0f * xy + x2i * y2, 1e-15f);
    float ov     = (c1 * xv + c2 * s * u) / den;

    float on2 = block_reduce_128(ov * ov, red);
    float on  = fmaxf(sqrtf(on2), 1e-15f);
    const float maxn = 1.0f - 4e-3f;                  // (1-PROJ_EPS)/sqrt(c)
    if (on > maxn) ov *= maxn / on;

    out[i * DD + t] = ov;
}

extern "C" void kernel_launch(void* const* d_in, const int* in_sizes, int n_in,
                              void* d_out, int out_size, void* d_ws, size_t ws_size,
                              hipStream_t stream) {
    const float* x     = (const float*)d_in[0];
    const float* adj   = (const float*)d_in[1];
    const float* att_w = (const float*)d_in[2];
    const float* att_b = (const float*)d_in[3];
    float* out = (float*)d_out;

    float* ws    = (float*)d_ws;
    float* x2a   = ws;                 // 768
    float* sL    = ws + NN;            // 768
    float* sR    = ws + 2 * NN;        // 768
    float* rowA  = ws + 3 * NN;        // 768
    int*   cnt   = (int*)(ws + 4 * NN);           // 768 ints
    int*   Jlist = (int*)(ws + 5 * NN);           // 768*CAP ints
    float* Blist = ws + 5 * NN + NN * CAP;        // 768*CAP floats

    precompute_kernel<<<NN, DD, 0, stream>>>(x, att_w, x2a, sL, sR);
    pair_kernel<<<NN, 256, 0, stream>>>(x, adj, x2a, sL, sR, att_b, rowA, cnt, Jlist, Blist);
    agg_kernel<<<NN, DD, 0, stream>>>(x, x2a, rowA, cnt, Jlist, Blist, out);
}